// Round 17
// baseline (34.666 us; speedup 1.0000x reference)
//
#include <hip/hip_runtime.h>
#include <hip/hip_bf16.h>
#include <math.h>

#define EMBED 128
#define VOCAB 32000
#define MEMN  50
#define BATCH 16
#define NQ    10
#define SQ    20
#define SS    40
#define BN    (BATCH*NQ)   // 160
#define NHOPS 3
#define NV    64           // vocab rows per k_out block
#define NST   (BATCH*MEMN) // 800 story items

typedef short v8s __attribute__((ext_vector_type(8)));
typedef float v4f __attribute__((ext_vector_type(4)));

#define MFMA16 __builtin_amdgcn_mfma_f32_16x16x32_bf16

__device__ __forceinline__ float posw(int j, int J, int k) {
    float jf = (float)(j + 1) / (float)J;
    return 1.0f - jf - ((float)(k + 1) / (float)EMBED) * (1.0f - 2.0f * jf);
}

__device__ __forceinline__ short f2bf(float f) {
    __hip_bfloat16 h = __float2bfloat16(f);
    return *(short*)&h;
}

// ---- Kernel 1 v8: story A -> memb [0,800) | story C -> OHm [800,1600) ----
// OHm[r,d] = sum_k outm[r,k]*Hw[d,k]  (the only way hops consumes outm:
// P·(outm@Hw^T) == (P·outm)@Hw^T). Removes the H-matvec from the hop loop.
__global__ void k_embed(const int* __restrict__ story,
                        const float* __restrict__ Aw, const float* __restrict__ Cw,
                        const float* __restrict__ TA, const float* __restrict__ TC,
                        const float* __restrict__ Hw,
                        float* __restrict__ memb, float* __restrict__ OHm) {
    __shared__ float lrow[EMBED];
    int blk = blockIdx.x;
    int t = threadIdx.x;   // 128
    if (blk < NST) {
        int br = blk;
        int r = br % MEMN;
        float ma = TA[r * EMBED + t];
        const int* toks = story + br * SS;
        #pragma unroll 4
        for (int s = 0; s < SS; ++s) {
            int tok = toks[s];
            ma += Aw[tok * EMBED + t] * posw(s, SS, t);
        }
        memb[br * EMBED + t] = ma;
    } else {
        int br = blk - NST;
        int r = br % MEMN;
        float mc = TC[r * EMBED + t];
        const int* toks = story + br * SS;
        #pragma unroll 4
        for (int s = 0; s < SS; ++s) {
            int tok = toks[s];
            mc += Cw[tok * EMBED + t] * posw(s, SS, t);
        }
        lrow[t] = mc;
        __syncthreads();
        // OHm row: thread d dots outm-row (LDS broadcast) with Hw row d (contiguous)
        const float4* hw4 = (const float4*)&Hw[(size_t)t * EMBED];
        float a0 = 0.f, a1 = 0.f, a2 = 0.f, a3 = 0.f;
        #pragma unroll 8
        for (int j = 0; j < 32; ++j) {
            float4 wv = hw4[j];
            int k = j << 2;
            a0 += lrow[k]     * wv.x;
            a1 += lrow[k + 1] * wv.y;
            a2 += lrow[k + 2] * wv.z;
            a3 += lrow[k + 3] * wv.w;
        }
        OHm[br * EMBED + t] = (a0 + a1) + (a2 + a3);
    }
}

// ---- Kernel 2 v8: hops with precomputed OHm. 160 blocks x 512 thr.
// Query embedding gathered in-block (no cross-block dep); 3 barriers/hop.
__global__ __launch_bounds__(512) void k_hops(const int* __restrict__ cq,
                                              const float* __restrict__ Bw,
                                              const float* __restrict__ memb,
                                              const float* __restrict__ OHm,
                                              const float* __restrict__ Hb,
                                              __hip_bfloat16* __restrict__ stateb) {
    __shared__ float lmem[MEMN][EMBED + 1];
    __shared__ float lOH[MEMN][EMBED + 1];
    __shared__ float lstate[EMBED];
    __shared__ float lqp[4][EMBED];
    __shared__ float lpart[8][52];
    __shared__ float lprobs[52];

    int bn = blockIdx.x;
    int b  = bn / NQ;
    int t  = threadIdx.x;   // 512
    int w  = t >> 6;        // wave 0..7
    int l  = t & 63;
    int d  = t & 127;
    int sg = t >> 7;        // 0..3

    // ---- stage batch memories + own-query embedding partials ----
    {
        const float4* mb4 = (const float4*)(memb + (size_t)b * MEMN * EMBED);
        const float4* oh4 = (const float4*)(OHm  + (size_t)b * MEMN * EMBED);
        for (int i = t; i < MEMN * EMBED / 4; i += 512) {
            int r = i >> 5, c = (i & 31) << 2;
            float4 v = mb4[i];
            lmem[r][c] = v.x; lmem[r][c+1] = v.y; lmem[r][c+2] = v.z; lmem[r][c+3] = v.w;
            float4 u = oh4[i];
            lOH[r][c] = u.x; lOH[r][c+1] = u.y; lOH[r][c+2] = u.z; lOH[r][c+3] = u.w;
        }
        // query: subgroup sg covers tokens {sg, sg+4, ..., sg+16}
        const int* toks = cq + bn * SQ;
        float acc = 0.f;
        #pragma unroll
        for (int i = 0; i < SQ / 4; ++i) {
            int s = sg + (i << 2);
            int tok = toks[s];
            acc += Bw[(size_t)tok * EMBED + d] * posw(s, SQ, d);
        }
        lqp[sg][d] = acc;
    }
    float hbd = (t < EMBED) ? Hb[t] : 0.f;
    __syncthreads();
    if (t < EMBED)
        lstate[t] = (lqp[0][t] + lqp[1][t]) + (lqp[2][t] + lqp[3][t]);
    __syncthreads();

    for (int hop = 0; hop < NHOPS; ++hop) {
        // logits split-K-8: wave w covers dims [w*16, w*16+16), lane l = row
        if (l < MEMN) {
            int d0 = w << 4;
            float a0 = 0.f, a1 = 0.f, a2 = 0.f, a3 = 0.f;
            #pragma unroll
            for (int j = 0; j < 16; j += 4) {
                a0 += lmem[l][d0 + j]     * lstate[d0 + j];
                a1 += lmem[l][d0 + j + 1] * lstate[d0 + j + 1];
                a2 += lmem[l][d0 + j + 2] * lstate[d0 + j + 2];
                a3 += lmem[l][d0 + j + 3] * lstate[d0 + j + 3];
            }
            lpart[w][l] = (a0 + a1) + (a2 + a3);
        }
        __syncthreads();
        // softmax in wave 0
        if (t < 64) {
            float lg = -1e30f;
            if (t < MEMN) {
                float s0 = (lpart[0][t] + lpart[1][t]) + (lpart[2][t] + lpart[3][t]);
                float s1 = (lpart[4][t] + lpart[5][t]) + (lpart[6][t] + lpart[7][t]);
                lg = s0 + s1;
            }
            float mx = lg;
            #pragma unroll
            for (int off = 32; off; off >>= 1) mx = fmaxf(mx, __shfl_xor(mx, off, 64));
            float e = (t < MEMN) ? __expf(lg - mx) : 0.f;
            float ss = e;
            #pragma unroll
            for (int off = 32; off; off >>= 1) ss += __shfl_xor(ss, off, 64);
            if (t < MEMN) lprobs[t] = e / ss;
        }
        __syncthreads();
        // state update: state'[d] = Hb[d] + state[d] + sum_r p_r*OHm[r,d]
        if (t < EMBED) {
            float a0 = 0.f, a1 = 0.f, a2 = 0.f, a3 = 0.f;
            #pragma unroll
            for (int r = 0; r < 48; r += 4) {
                a0 += lprobs[r]     * lOH[r][t];
                a1 += lprobs[r + 1] * lOH[r + 1][t];
                a2 += lprobs[r + 2] * lOH[r + 2][t];
                a3 += lprobs[r + 3] * lOH[r + 3][t];
            }
            a0 += lprobs[48] * lOH[48][t];
            a1 += lprobs[49] * lOH[49][t];
            lstate[t] = hbd + lstate[t] + (a0 + a1) + (a2 + a3);
        }
        __syncthreads();
    }
    if (t < EMBED)
        stateb[bn * EMBED + t] = __float2bfloat16(lstate[t]);
}

// ---- Kernel 3 (R15-exact): MFMA GEMM out[160,32000] ----
__global__ __launch_bounds__(256) void k_out(const __hip_bfloat16* __restrict__ stateb,
                                             const float* __restrict__ outw,
                                             float* __restrict__ out) {
    __shared__ __align__(16) __hip_bfloat16 Alds[BN][EMBED + 8];
    __shared__ __align__(16) __hip_bfloat16 Blds[NV][EMBED + 8];
    int t = threadIdx.x;
    int vbase = blockIdx.x * NV;

    #pragma unroll
    for (int i = 0; i < 10; ++i) {
        int e = t + i * 256;
        int row = e >> 4, c8 = (e & 15) << 3;
        *(int4*)&Alds[row][c8] = *(const int4*)&stateb[row * EMBED + c8];
    }
    #pragma unroll
    for (int i = 0; i < 8; ++i) {
        int e = t + i * 256;
        int row = e >> 5, c4 = (e & 31) << 2;
        float4 w = *(const float4*)&outw[(size_t)(vbase + row) * EMBED + c4];
        short4 p;
        p.x = f2bf(w.x); p.y = f2bf(w.y); p.z = f2bf(w.z); p.w = f2bf(w.w);
        *(short4*)&Blds[row][c4] = p;
    }
    __syncthreads();

    int wv = t >> 6;
    int l = t & 63;
    int col16 = l & 15;
    int kg = l >> 4;

    v8s bfrag[4];
    #pragma unroll
    for (int k4 = 0; k4 < 4; ++k4)
        bfrag[k4] = *(v8s*)&Blds[(wv << 4) + col16][k4 * 32 + kg * 8];

    v4f acc[10];
    #pragma unroll
    for (int m = 0; m < 10; ++m) acc[m] = (v4f){0.f, 0.f, 0.f, 0.f};

    #pragma unroll
    for (int k4 = 0; k4 < 4; ++k4) {
        #pragma unroll
        for (int m = 0; m < 10; ++m) {
            v8s af = *(v8s*)&Alds[m * 16 + col16][k4 * 32 + kg * 8];
            acc[m] = MFMA16(af, bfrag[k4], acc[m], 0, 0, 0);
        }
    }

    int colg = vbase + (wv << 4) + col16;
    #pragma unroll
    for (int m = 0; m < 10; ++m) {
        #pragma unroll
        for (int i = 0; i < 4; ++i) {
            out[(size_t)(m * 16 + kg * 4 + i) * VOCAB + colg] = acc[m][i];
        }
    }
}

extern "C" void kernel_launch(void* const* d_in, const int* in_sizes, int n_in,
                              void* d_out, int out_size, void* d_ws, size_t ws_size,
                              hipStream_t stream) {
    const int*   ctx_query = (const int*)  d_in[0];
    const int*   story     = (const int*)  d_in[1];
    const float* A_w       = (const float*)d_in[2];
    const float* C_w       = (const float*)d_in[3];
    const float* B_w       = (const float*)d_in[4];
    const float* H_w       = (const float*)d_in[5];
    const float* H_b       = (const float*)d_in[6];
    const float* out_w     = (const float*)d_in[7];
    const float* TA        = (const float*)d_in[8];
    const float* TC        = (const float*)d_in[9];
    float* out = (float*)d_out;

    float* ws   = (float*)d_ws;
    float* memb = ws;                                    // 800*128 f32
    float* OHm  = memb + NST * EMBED;                    // 800*128 f32
    __hip_bfloat16* stateb = (__hip_bfloat16*)(OHm + NST * EMBED); // 160*128 bf16

    k_embed<<<NST * 2, 128, 0, stream>>>(
        story, A_w, C_w, TA, TC, H_w, memb, OHm);
    k_hops<<<BN, 512, 0, stream>>>(
        ctx_query, B_w, memb, OHm, H_b, stateb);
    k_out<<<VOCAB / NV, 256, 0, stream>>>(stateb, out_w, out);
}

// Round 18
// 29.823 us; speedup vs baseline: 1.1624x; 1.1624x over previous
//
#include <hip/hip_runtime.h>
#include <hip/hip_bf16.h>
#include <hip/hip_cooperative_groups.h>
#include <math.h>

namespace cg = cooperative_groups;

#define EMBED 128
#define VOCAB 32000
#define MEMN  50
#define BATCH 16
#define NQ    10
#define SQ    20
#define SS    40
#define BN    (BATCH*NQ)   // 160
#define NHOPS 3
#define NV    64           // vocab cols per out-tile
#define NST   (BATCH*MEMN) // 800
#define NOUT  (VOCAB/NV)   // 500
#define MGRID 512

typedef short v8s __attribute__((ext_vector_type(8)));
typedef float v4f __attribute__((ext_vector_type(4)));

#define MFMA16 __builtin_amdgcn_mfma_f32_16x16x32_bf16

__device__ __forceinline__ float posw(int j, int J, int k) {
    float jf = (float)(j + 1) / (float)J;
    return 1.0f - jf - ((float)(k + 1) / (float)EMBED) * (1.0f - 2.0f * jf);
}

__device__ __forceinline__ short f2bf(float f) {
    __hip_bfloat16 h = __float2bfloat16(f);
    return *(short*)&h;
}

// ===================== MEGA: 1 node, 2 grid.sync() =====================
// Phase E: embed (960 items, 2 per block) | sync |
// Phase H: hops v6 (blk<160)  ||  out_w pre-stage (160<=blk<500) | sync |
// Phase O: classifier GEMM tile per block (blk<500).
union __align__(16) Smem {
    struct {
        float lmem[MEMN][EMBED + 1];
        float lout[MEMN][EMBED + 1];
        float lstate[EMBED];
        float lpart[4][52];
        float lprobs[52];
        float lrespp[2][EMBED];
        float lHp[2][EMBED];
    } h;                                       // 55.2 KB
    struct {
        short Alds[BN][EMBED + 8];
        short Blds[NV][EMBED + 8];
    } o;                                       // 60.9 KB
};

__global__ __launch_bounds__(256) void mega(
    const int* __restrict__ cq, const int* __restrict__ story,
    const float* __restrict__ Bw, const float* __restrict__ Aw,
    const float* __restrict__ Cw, const float* __restrict__ TA,
    const float* __restrict__ TC, const float* __restrict__ Hw,
    const float* __restrict__ Hb, const float* __restrict__ outw,
    float* __restrict__ state, float* __restrict__ memb,
    float* __restrict__ outb, __hip_bfloat16* __restrict__ stateb,
    float* __restrict__ out)
{
    __shared__ Smem sm;
    cg::grid_group grid = cg::this_grid();
    int blk = blockIdx.x;
    int t = threadIdx.x;    // 256

    // ---------------- Phase E: embedding (R16 body, 2 items/block) ----------
    {
        int half = t >> 7, th = t & 127;
        int item = blk * 2 + half;              // 0..1023, work < 960
        if (item < BN) {
            float acc = 0.f;
            const int* toks = cq + item * SQ;
            #pragma unroll
            for (int s = 0; s < SQ; ++s) {
                int tok = toks[s];
                acc += Bw[tok * EMBED + th] * posw(s, SQ, th);
            }
            state[item * EMBED + th] = acc;
        } else if (item < BN + NST) {
            int br = item - BN;
            int r = br % MEMN;
            float ma = TA[r * EMBED + th];
            float mc = TC[r * EMBED + th];
            const int* toks = story + br * SS;
            #pragma unroll 4
            for (int s = 0; s < SS; ++s) {
                int tok = toks[s];
                float w = posw(s, SS, th);
                ma += Aw[tok * EMBED + th] * w;
                mc += Cw[tok * EMBED + th] * w;
            }
            memb[br * EMBED + th] = ma;
            outb[br * EMBED + th] = mc;
        }
    }
    grid.sync();

    // ---------------- Phase H: hops (blk<160) || weight pre-stage -----------
    if (blk < BN) {
        int bn = blk;
        int b  = bn / NQ;
        int w  = t >> 6;    // wave 0..3
        int l  = t & 63;
        int d  = t & 127;
        int h  = t >> 7;    // half 0/1

        {
            const float4* mb4 = (const float4*)(memb + (size_t)b * MEMN * EMBED);
            const float4* ob4 = (const float4*)(outb + (size_t)b * MEMN * EMBED);
            for (int i = t; i < MEMN * EMBED / 4; i += 256) {
                int r = i >> 5, c = (i & 31) << 2;
                float4 v = mb4[i];
                sm.h.lmem[r][c] = v.x; sm.h.lmem[r][c+1] = v.y;
                sm.h.lmem[r][c+2] = v.z; sm.h.lmem[r][c+3] = v.w;
                float4 u = ob4[i];
                sm.h.lout[r][c] = u.x; sm.h.lout[r][c+1] = u.y;
                sm.h.lout[r][c+2] = u.z; sm.h.lout[r][c+3] = u.w;
            }
            if (t < EMBED) sm.h.lstate[t] = state[bn * EMBED + t];
        }
        float hbd = (t < EMBED) ? Hb[t] : 0.f;
        __syncthreads();

        for (int hop = 0; hop < NHOPS; ++hop) {
            if (l < MEMN) {
                int d0 = w << 5;
                float a0 = 0.f, a1 = 0.f, a2 = 0.f, a3 = 0.f;
                #pragma unroll
                for (int j = 0; j < 32; j += 4) {
                    a0 += sm.h.lmem[l][d0 + j]     * sm.h.lstate[d0 + j];
                    a1 += sm.h.lmem[l][d0 + j + 1] * sm.h.lstate[d0 + j + 1];
                    a2 += sm.h.lmem[l][d0 + j + 2] * sm.h.lstate[d0 + j + 2];
                    a3 += sm.h.lmem[l][d0 + j + 3] * sm.h.lstate[d0 + j + 3];
                }
                sm.h.lpart[w][l] = (a0 + a1) + (a2 + a3);
            }
            __syncthreads();
            if (t < 64) {
                float lg = (t < MEMN)
                    ? (sm.h.lpart[0][t] + sm.h.lpart[1][t]) +
                      (sm.h.lpart[2][t] + sm.h.lpart[3][t]) : -1e30f;
                float mx = lg;
                #pragma unroll
                for (int off = 32; off; off >>= 1) mx = fmaxf(mx, __shfl_xor(mx, off, 64));
                float e = (t < MEMN) ? __expf(lg - mx) : 0.f;
                float ss = e;
                #pragma unroll
                for (int off = 32; off; off >>= 1) ss += __shfl_xor(ss, off, 64);
                if (t < MEMN) sm.h.lprobs[t] = e / ss;
            }
            __syncthreads();
            {
                float r0 = 0.f, r1 = 0.f;
                int k0 = h * 25;
                #pragma unroll
                for (int k = 0; k < 24; k += 2) {
                    r0 += sm.h.lprobs[k0 + k]     * sm.h.lout[k0 + k][d];
                    r1 += sm.h.lprobs[k0 + k + 1] * sm.h.lout[k0 + k + 1][d];
                }
                r0 += sm.h.lprobs[k0 + 24] * sm.h.lout[k0 + 24][d];
                sm.h.lrespp[h][d] = r0 + r1;
            }
            __syncthreads();
            {
                int ks = h << 6;
                const float4* hw4 = (const float4*)&Hw[(size_t)d * EMBED + ks];
                float a0 = 0.f, a1 = 0.f, a2 = 0.f, a3 = 0.f;
                #pragma unroll
                for (int j = 0; j < 16; ++j) {
                    float4 wv = hw4[j];
                    int k = ks + (j << 2);
                    a0 += (sm.h.lrespp[0][k]     + sm.h.lrespp[1][k])     * wv.x;
                    a1 += (sm.h.lrespp[0][k + 1] + sm.h.lrespp[1][k + 1]) * wv.y;
                    a2 += (sm.h.lrespp[0][k + 2] + sm.h.lrespp[1][k + 2]) * wv.z;
                    a3 += (sm.h.lrespp[0][k + 3] + sm.h.lrespp[1][k + 3]) * wv.w;
                }
                sm.h.lHp[h][d] = (a0 + a1) + (a2 + a3);
            }
            __syncthreads();
            if (t < EMBED) {
                float ns = hbd + sm.h.lstate[t] + sm.h.lHp[0][t] + sm.h.lHp[1][t];
                sm.h.lstate[t] = ns;
            }
            __syncthreads();
        }
        if (t < EMBED)
            stateb[bn * EMBED + t] = __float2bfloat16(sm.h.lstate[t]);
    } else if (blk < NOUT) {
        // pre-stage this block's out_w tile (state-independent) under hops
        int vbase = blk * NV;
        #pragma unroll
        for (int i = 0; i < 8; ++i) {
            int e = t + i * 256;
            int row = e >> 5, c4 = (e & 31) << 2;
            float4 w = *(const float4*)&outw[(size_t)(vbase + row) * EMBED + c4];
            short4 p;
            p.x = f2bf(w.x); p.y = f2bf(w.y); p.z = f2bf(w.z); p.w = f2bf(w.w);
            *(short4*)&sm.o.Blds[row][c4] = p;
        }
    }
    grid.sync();

    // ---------------- Phase O: classifier GEMM (R16 k_out body) -------------
    if (blk < NOUT) {
        int vbase = blk * NV;
        if (blk < BN) {   // hops blocks stage weights now
            #pragma unroll
            for (int i = 0; i < 8; ++i) {
                int e = t + i * 256;
                int row = e >> 5, c4 = (e & 31) << 2;
                float4 w = *(const float4*)&outw[(size_t)(vbase + row) * EMBED + c4];
                short4 p;
                p.x = f2bf(w.x); p.y = f2bf(w.y); p.z = f2bf(w.z); p.w = f2bf(w.w);
                *(short4*)&sm.o.Blds[row][c4] = p;
            }
        }
        #pragma unroll
        for (int i = 0; i < 10; ++i) {
            int e = t + i * 256;
            int row = e >> 4, c8 = (e & 15) << 3;
            *(int4*)&sm.o.Alds[row][c8] = *(const int4*)&stateb[row * EMBED + c8];
        }
        __syncthreads();

        int wv = t >> 6;
        int l = t & 63;
        int col16 = l & 15;
        int kg = l >> 4;

        v8s bfrag[4];
        #pragma unroll
        for (int k4 = 0; k4 < 4; ++k4)
            bfrag[k4] = *(v8s*)&sm.o.Blds[(wv << 4) + col16][k4 * 32 + kg * 8];

        v4f acc[10];
        #pragma unroll
        for (int m = 0; m < 10; ++m) acc[m] = (v4f){0.f, 0.f, 0.f, 0.f};

        #pragma unroll
        for (int k4 = 0; k4 < 4; ++k4) {
            #pragma unroll
            for (int m = 0; m < 10; ++m) {
                v8s af = *(v8s*)&sm.o.Alds[m * 16 + col16][k4 * 32 + kg * 8];
                acc[m] = MFMA16(af, bfrag[k4], acc[m], 0, 0, 0);
            }
        }

        int colg = vbase + (wv << 4) + col16;
        #pragma unroll
        for (int m = 0; m < 10; ++m) {
            #pragma unroll
            for (int i = 0; i < 4; ++i)
                out[(size_t)(m * 16 + kg * 4 + i) * VOCAB + colg] = acc[m][i];
        }
    }
}

// ===================== Fallback: R16-exact 3-kernel path =====================
__global__ void k_embed(const int* __restrict__ cq, const int* __restrict__ story,
                        const float* __restrict__ Bw, const float* __restrict__ Aw,
                        const float* __restrict__ Cw, const float* __restrict__ TA,
                        const float* __restrict__ TC,
                        float* __restrict__ state, float* __restrict__ memb,
                        float* __restrict__ outb) {
    int blk = blockIdx.x;
    int t = threadIdx.x;   // 128
    if (blk < BN) {
        float acc = 0.f;
        #pragma unroll
        for (int s = 0; s < SQ; ++s) {
            int tok = cq[blk * SQ + s];
            acc += Bw[tok * EMBED + t] * posw(s, SQ, t);
        }
        state[blk * EMBED + t] = acc;
    } else {
        int br = blk - BN;
        int r = br % MEMN;
        float ma = TA[r * EMBED + t];
        float mc = TC[r * EMBED + t];
        const int* toks = story + br * SS;
        #pragma unroll 4
        for (int s = 0; s < SS; ++s) {
            int tok = toks[s];
            float w = posw(s, SS, t);
            ma += Aw[tok * EMBED + t] * w;
            mc += Cw[tok * EMBED + t] * w;
        }
        memb[br * EMBED + t] = ma;
        outb[br * EMBED + t] = mc;
    }
}

__global__ __launch_bounds__(512) void k_hops(const float* __restrict__ memb,
                                              const float* __restrict__ outb,
                                              const float* __restrict__ Hw,
                                              const float* __restrict__ Hb,
                                              const float* __restrict__ state,
                                              __hip_bfloat16* __restrict__ stateb) {
    __shared__ float lmem[MEMN][EMBED + 1];
    __shared__ float lout[MEMN][EMBED + 1];
    __shared__ float lstate[EMBED];
    __shared__ float lpart[8][52];
    __shared__ float lprobs[52];
    __shared__ float lrespp[4][EMBED];
    __shared__ float lHp[4][EMBED];

    int bn = blockIdx.x;
    int b  = bn / NQ;
    int t  = threadIdx.x;   // 512
    int w  = t >> 6;
    int l  = t & 63;
    int d  = t & 127;
    int g  = t >> 7;

    {
        const float4* mb4 = (const float4*)(memb + (size_t)b * MEMN * EMBED);
        const float4* ob4 = (const float4*)(outb + (size_t)b * MEMN * EMBED);
        for (int i = t; i < MEMN * EMBED / 4; i += 512) {
            int r = i >> 5, c = (i & 31) << 2;
            float4 v = mb4[i];
            lmem[r][c] = v.x; lmem[r][c+1] = v.y; lmem[r][c+2] = v.z; lmem[r][c+3] = v.w;
            float4 u = ob4[i];
            lout[r][c] = u.x; lout[r][c+1] = u.y; lout[r][c+2] = u.z; lout[r][c+3] = u.w;
        }
        if (t < EMBED) lstate[t] = state[bn * EMBED + t];
    }
    float hbd = (t < EMBED) ? Hb[t] : 0.f;
    __syncthreads();

    for (int hop = 0; hop < NHOPS; ++hop) {
        if (l < MEMN) {
            int d0 = w << 4;
            float a0 = 0.f, a1 = 0.f, a2 = 0.f, a3 = 0.f;
            #pragma unroll
            for (int j = 0; j < 16; j += 4) {
                a0 += lmem[l][d0 + j]     * lstate[d0 + j];
                a1 += lmem[l][d0 + j + 1] * lstate[d0 + j + 1];
                a2 += lmem[l][d0 + j + 2] * lstate[d0 + j + 2];
                a3 += lmem[l][d0 + j + 3] * lstate[d0 + j + 3];
            }
            lpart[w][l] = (a0 + a1) + (a2 + a3);
        }
        __syncthreads();
        if (t < 64) {
            float lg = -1e30f;
            if (t < MEMN) {
                float s0 = (lpart[0][t] + lpart[1][t]) + (lpart[2][t] + lpart[3][t]);
                float s1 = (lpart[4][t] + lpart[5][t]) + (lpart[6][t] + lpart[7][t]);
                lg = s0 + s1;
            }
            float mx = lg;
            #pragma unroll
            for (int off = 32; off; off >>= 1) mx = fmaxf(mx, __shfl_xor(mx, off, 64));
            float e = (t < MEMN) ? __expf(lg - mx) : 0.f;
            float ss = e;
            #pragma unroll
            for (int off = 32; off; off >>= 1) ss += __shfl_xor(ss, off, 64);
            if (t < MEMN) lprobs[t] = e / ss;
        }
        __syncthreads();
        {
            float r0 = 0.f, r1 = 0.f;
            #pragma unroll
            for (int k = 0; k + 4 < MEMN; k += 8) {
                int ra = g + k, rb = g + k + 4;
                r0 += lprobs[ra] * lout[ra][d];
                r1 += lprobs[rb] * lout[rb][d];
            }
            if (g < 2) { int ra = g + 48; r0 += lprobs[ra] * lout[ra][d]; }
            lrespp[g][d] = r0 + r1;
        }
        __syncthreads();
        {
            int ks = g << 5;
            const float4* hw4 = (const float4*)&Hw[(size_t)d * EMBED + ks];
            float a0 = 0.f, a1 = 0.f, a2 = 0.f, a3 = 0.f;
            #pragma unroll
            for (int j = 0; j < 8; ++j) {
                float4 wv = hw4[j];
                int k = ks + (j << 2);
                float v0 = (lrespp[0][k]     + lrespp[1][k])     + (lrespp[2][k]     + lrespp[3][k]);
                float v1 = (lrespp[0][k + 1] + lrespp[1][k + 1]) + (lrespp[2][k + 1] + lrespp[3][k + 1]);
                float v2 = (lrespp[0][k + 2] + lrespp[1][k + 2]) + (lrespp[2][k + 2] + lrespp[3][k + 2]);
                float v3 = (lrespp[0][k + 3] + lrespp[1][k + 3]) + (lrespp[2][k + 3] + lrespp[3][k + 3]);
                a0 += v0 * wv.x; a1 += v1 * wv.y; a2 += v2 * wv.z; a3 += v3 * wv.w;
            }
            lHp[g][d] = (a0 + a1) + (a2 + a3);
        }
        __syncthreads();
        if (t < EMBED) {
            float ns = hbd + lstate[t]
                     + (lHp[0][t] + lHp[1][t]) + (lHp[2][t] + lHp[3][t]);
            lstate[t] = ns;
        }
        __syncthreads();
    }
    if (t < EMBED)
        stateb[bn * EMBED + t] = __float2bfloat16(lstate[t]);
}

__global__ __launch_bounds__(256) void k_out(const __hip_bfloat16* __restrict__ stateb,
                                             const float* __restrict__ outw,
                                             float* __restrict__ out) {
    __shared__ __align__(16) __hip_bfloat16 Alds[BN][EMBED + 8];
    __shared__ __align__(16) __hip_bfloat16 Blds[NV][EMBED + 8];
    int t = threadIdx.x;
    int vbase = blockIdx.x * NV;

    #pragma unroll
    for (int i = 0; i < 10; ++i) {
        int e = t + i * 256;
        int row = e >> 4, c8 = (e & 15) << 3;
        *(int4*)&Alds[row][c8] = *(const int4*)&stateb[row * EMBED + c8];
    }
    #pragma unroll
    for (int i = 0; i < 8; ++i) {
        int e = t + i * 256;
        int row = e >> 5, c4 = (e & 31) << 2;
        float4 w = *(const float4*)&outw[(size_t)(vbase + row) * EMBED + c4];
        short4 p;
        p.x = f2bf(w.x); p.y = f2bf(w.y); p.z = f2bf(w.z); p.w = f2bf(w.w);
        *(short4*)&Blds[row][c4] = p;
    }
    __syncthreads();

    int wv = t >> 6;
    int l = t & 63;
    int col16 = l & 15;
    int kg = l >> 4;

    v8s bfrag[4];
    #pragma unroll
    for (int k4 = 0; k4 < 4; ++k4)
        bfrag[k4] = *(v8s*)&Blds[(wv << 4) + col16][k4 * 32 + kg * 8];

    v4f acc[10];
    #pragma unroll
    for (int m = 0; m < 10; ++m) acc[m] = (v4f){0.f, 0.f, 0.f, 0.f};

    #pragma unroll
    for (int k4 = 0; k4 < 4; ++k4) {
        #pragma unroll
        for (int m = 0; m < 10; ++m) {
            v8s af = *(v8s*)&Alds[m * 16 + col16][k4 * 32 + kg * 8];
            acc[m] = MFMA16(af, bfrag[k4], acc[m], 0, 0, 0);
        }
    }

    int colg = vbase + (wv << 4) + col16;
    #pragma unroll
    for (int m = 0; m < 10; ++m) {
        #pragma unroll
        for (int i = 0; i < 4; ++i) {
            out[(size_t)(m * 16 + kg * 4 + i) * VOCAB + colg] = acc[m][i];
        }
    }
}

extern "C" void kernel_launch(void* const* d_in, const int* in_sizes, int n_in,
                              void* d_out, int out_size, void* d_ws, size_t ws_size,
                              hipStream_t stream) {
    const int*   ctx_query = (const int*)  d_in[0];
    const int*   story     = (const int*)  d_in[1];
    const float* A_w       = (const float*)d_in[2];
    const float* C_w       = (const float*)d_in[3];
    const float* B_w       = (const float*)d_in[4];
    const float* H_w       = (const float*)d_in[5];
    const float* H_b       = (const float*)d_in[6];
    const float* out_w     = (const float*)d_in[7];
    const float* TA        = (const float*)d_in[8];
    const float* TC        = (const float*)d_in[9];
    float* out = (float*)d_out;

    float* ws    = (float*)d_ws;
    float* state = ws;                                   // 160*128 f32
    float* memb  = state + BN * EMBED;                   // 800*128 f32
    float* outb  = memb + NST * EMBED;                   // 800*128 f32
    __hip_bfloat16* stateb = (__hip_bfloat16*)(outb + NST * EMBED); // 160*128 bf16

    int maxB = 0;
    bool coop = (hipOccupancyMaxActiveBlocksPerMultiprocessor(&maxB, mega, 256, 0)
                 == hipSuccess) && (maxB >= 2);
    if (coop) {
        void* args[] = {
            (void*)&ctx_query, (void*)&story, (void*)&B_w, (void*)&A_w, (void*)&C_w,
            (void*)&TA, (void*)&TC, (void*)&H_w, (void*)&H_b, (void*)&out_w,
            (void*)&state, (void*)&memb, (void*)&outb, (void*)&stateb, (void*)&out
        };
        hipError_t rc = hipLaunchCooperativeKernel((const void*)mega, dim3(MGRID),
                                                   dim3(256), args, 0, stream);
        if (rc != hipSuccess) { (void)hipGetLastError(); coop = false; }
    }
    if (!coop) {
        k_embed<<<BN + NST, 128, 0, stream>>>(
            ctx_query, story, B_w, A_w, C_w, TA, TC, state, memb, outb);
        k_hops<<<BN, 512, 0, stream>>>(memb, outb, H_w, H_b, state, stateb);
        k_out<<<VOCAB / NV, 256, 0, stream>>>(stateb, out_w, out);
    }
}